// Round 1
// baseline (1273.656 us; speedup 1.0000x reference)
//
#include <hip/hip_runtime.h>
#include <hip/hip_bf16.h>

// Problem constants (match reference)
#define N_ATOMS 20000
#define N_EDGES 400000
#define NCH 4
#define F_IN 128
#define S_OUT 32

// ---------- helpers ----------
__device__ __forceinline__ float silu_f(float v) { return v / (1.f + __expf(-v)); }

// monotone float<->uint encoding for atomicMax on floats (incl. negatives)
__device__ __forceinline__ unsigned enc_f(float f) {
    unsigned u = __float_as_uint(f);
    return (u & 0x80000000u) ? ~u : (u | 0x80000000u);
}
__device__ __forceinline__ float dec_f(unsigned u) {
    return __uint_as_float((u & 0x80000000u) ? (u ^ 0x80000000u) : ~u);
}

// ---------- fill ----------
__global__ void fill_kernel(float* __restrict__ p, int n, float v) {
    int i = blockIdx.x * blockDim.x + threadIdx.x;
    int stride = gridDim.x * blockDim.x;
    for (; i < n; i += stride) p[i] = v;
}

// ---------- LayerNorm over last dim (128) ----------
__global__ __launch_bounds__(256) void ln_kernel(const float* __restrict__ x,
                                                 const float* __restrict__ gamma,
                                                 const float* __restrict__ beta,
                                                 float* __restrict__ out) {
    int row = blockIdx.x * 4 + (threadIdx.x >> 6);  // row in [0, N*C)
    int l = threadIdx.x & 63;
    const float* xr = x + (size_t)row * F_IN;
    float v0 = xr[l], v1 = xr[l + 64];
    float s = v0 + v1, sq = v0 * v0 + v1 * v1;
#pragma unroll
    for (int off = 32; off; off >>= 1) {
        s += __shfl_xor(s, off);
        sq += __shfl_xor(sq, off);
    }
    float mu = s * (1.f / 128.f);
    float var = sq * (1.f / 128.f) - mu * mu;
    float rs = rsqrtf(var + 1e-5f);
    float* orow = out + (size_t)row * F_IN;
    orow[l]      = (v0 - mu) * rs * gamma[l]      + beta[l];
    orow[l + 64] = (v1 - mu) * rs * gamma[l + 64] + beta[l + 64];
}

// ---------- per-channel projection: out[n,c,o]=sum_k in[n,c,k]W[c,k,o]; plus attn dots ----------
template <int FIN, bool SILU_IN, bool ATT>
__global__ __launch_bounds__(256) void proj_kernel(const float* __restrict__ in,
                                                   const float* __restrict__ W,
                                                   const float* __restrict__ a_src,
                                                   const float* __restrict__ a_dst,
                                                   float* __restrict__ out,
                                                   float* __restrict__ es,
                                                   float* __restrict__ ed) {
    __shared__ float Wl[FIN * 64];
    __shared__ float inl[32 * FIN];
    const int tid = threadIdx.x;
    const int n0 = blockIdx.x * 32;
    const int o = tid & 63;
    const int w = tid >> 6;

    for (int c = 0; c < NCH; ++c) {
        for (int i = tid; i < FIN * 64; i += 256) Wl[i] = W[c * FIN * 64 + i];
        for (int i = tid; i < 32 * FIN; i += 256) {
            int nl = i / FIN, k = i - nl * FIN;
            float v = in[(size_t)(n0 + nl) * (NCH * FIN) + c * FIN + k];
            if (SILU_IN) v = silu_f(v);
            inl[i] = v;
        }
        __syncthreads();

        float as = 0.f, ad = 0.f;
        if (ATT) { as = a_src[c * 64 + o]; ad = a_dst[c * 64 + o]; }

        float acc[8];
#pragma unroll
        for (int i = 0; i < 8; ++i) acc[i] = 0.f;
#pragma unroll 4
        for (int k = 0; k < FIN; ++k) {
            float wv = Wl[k * 64 + o];
#pragma unroll
            for (int i = 0; i < 8; ++i) acc[i] += inl[(w * 8 + i) * FIN + k] * wv;
        }
#pragma unroll
        for (int i = 0; i < 8; ++i) {
            int n = n0 + w * 8 + i;
            out[(size_t)n * 256 + c * 64 + o] = acc[i];
            if (ATT) {
                float vs = acc[i] * as, vd = acc[i] * ad;
#pragma unroll
                for (int off = 32; off; off >>= 1) {
                    vs += __shfl_xor(vs, off);
                    vd += __shfl_xor(vd, off);
                }
                if (o == 0) { es[n * NCH + c] = vs; ed[n * NCH + c] = vd; }
            }
        }
        __syncthreads();
    }
}

// ---------- edge pass 1: logits + segment max ----------
__global__ __launch_bounds__(256) void edge_max_kernel(const int* __restrict__ ei,
                                                       const float* __restrict__ es,
                                                       const float* __restrict__ ed,
                                                       unsigned* __restrict__ mm,
                                                       float* __restrict__ pl, int E) {
    int e = blockIdx.x * 256 + threadIdx.x;
    if (e >= E) return;
    int s = ei[e], d = ei[E + e];
    float4 a = *(const float4*)(es + (size_t)s * 4);
    float4 b = *(const float4*)(ed + (size_t)d * 4);
    float4 l;
    l.x = a.x + b.x; l.x = l.x >= 0.f ? l.x : 0.2f * l.x;
    l.y = a.y + b.y; l.y = l.y >= 0.f ? l.y : 0.2f * l.y;
    l.z = a.z + b.z; l.z = l.z >= 0.f ? l.z : 0.2f * l.z;
    l.w = a.w + b.w; l.w = l.w >= 0.f ? l.w : 0.2f * l.w;
    *(float4*)(pl + (size_t)e * 4) = l;
    atomicMax(mm + d * 4 + 0, enc_f(l.x));
    atomicMax(mm + d * 4 + 1, enc_f(l.y));
    atomicMax(mm + d * 4 + 2, enc_f(l.z));
    atomicMax(mm + d * 4 + 3, enc_f(l.w));
}

// ---------- edge pass 2: exp + segment sum ----------
__global__ __launch_bounds__(256) void edge_sum_kernel(const int* __restrict__ ei,
                                                       const unsigned* __restrict__ mm,
                                                       float* __restrict__ pl,
                                                       float* __restrict__ den, int E) {
    int e = blockIdx.x * 256 + threadIdx.x;
    if (e >= E) return;
    int d = ei[E + e];
    float4 l = *(const float4*)(pl + (size_t)e * 4);
    uint4 mu = *(const uint4*)(mm + (size_t)d * 4);
    float4 ex;
    ex.x = __expf(l.x - dec_f(mu.x));
    ex.y = __expf(l.y - dec_f(mu.y));
    ex.z = __expf(l.z - dec_f(mu.z));
    ex.w = __expf(l.w - dec_f(mu.w));
    *(float4*)(pl + (size_t)e * 4) = ex;
    atomicAdd(den + d * 4 + 0, ex.x);
    atomicAdd(den + d * 4 + 1, ex.y);
    atomicAdd(den + d * 4 + 2, ex.z);
    atomicAdd(den + d * 4 + 3, ex.w);
}

// ---------- edge pass 3: alpha * h[src] scattered into out[dst] ----------
// one block per edge; 4 waves = 4 channels; 64 lanes = 64 features
__global__ __launch_bounds__(256) void edge_msg_kernel(const int* __restrict__ ei,
                                                       const float* __restrict__ pl,
                                                       const float* __restrict__ den,
                                                       const float* __restrict__ h,
                                                       float* __restrict__ out, int E) {
    int e = blockIdx.x;
    int c = threadIdx.x >> 6, o = threadIdx.x & 63;
    int s = ei[e], d = ei[E + e];
    float alpha = pl[(size_t)e * 4 + c] / (den[(size_t)d * 4 + c] + 1e-16f);
    float hv = h[(size_t)s * 256 + c * 64 + o];
    atomicAdd(out + (size_t)d * 256 + c * 64 + o, alpha * hv);
}

// ---------- MLP + channel-sum + structure segment-sum ----------
__global__ __launch_bounds__(256) void mlp_kernel(const float* __restrict__ in,
                                                  const float* __restrict__ W1,
                                                  const float* __restrict__ W2,
                                                  const float* __restrict__ W3,
                                                  const int* __restrict__ bat,
                                                  float* __restrict__ out, int N) {
    int n = blockIdx.x * 256 + threadIdx.x;
    bool act = n < N;
    int nn = act ? n : N - 1;
    float y = 0.f;
    for (int c = 0; c < NCH; ++c) {
        const float* ip = in + (size_t)nn * 256 + c * 64;
        const float* w1 = W1 + c * 4096;
        const float* w2 = W2 + c * 2048;
        const float* w3 = W3 + c * 32;
        float t1[64];
#pragma unroll
        for (int o = 0; o < 64; ++o) t1[o] = 0.f;
#pragma unroll
        for (int k = 0; k < 64; ++k) {
            float ak = silu_f(ip[k]);
#pragma unroll
            for (int o = 0; o < 64; ++o) t1[o] += ak * w1[k * 64 + o];
        }
        float t2[32];
#pragma unroll
        for (int o = 0; o < 32; ++o) t2[o] = 0.f;
#pragma unroll
        for (int k = 0; k < 64; ++k) {
            float tk = silu_f(t1[k]);
#pragma unroll
            for (int o = 0; o < 32; ++o) t2[o] += tk * w2[k * 32 + o];
        }
#pragma unroll
        for (int o = 0; o < 32; ++o) y += silu_f(t2[o]) * w3[o];
    }
    // energies[b] += y / sqrt(4) / 20  = y * 0.025
    float contrib = act ? y * 0.025f : 0.f;
    int b = bat[nn];
    int b0 = __shfl(b, 0);
    bool uni = __all(b == b0);
    if (uni) {
        float t = contrib;
#pragma unroll
        for (int off = 32; off; off >>= 1) t += __shfl_xor(t, off);
        if ((threadIdx.x & 63) == 0) atomicAdd(out + b0, t);
    } else {
        if (act) atomicAdd(out + b, contrib);
    }
}

extern "C" void kernel_launch(void* const* d_in, const int* in_sizes, int n_in,
                              void* d_out, int out_size, void* d_ws, size_t ws_size,
                              hipStream_t stream) {
    const float* x     = (const float*)d_in[0];
    const int*   ei    = (const int*)d_in[1];
    const int*   bat   = (const int*)d_in[2];
    const float* gamma = (const float*)d_in[3];
    const float* beta  = (const float*)d_in[4];
    const float* Wc1   = (const float*)d_in[5];
    const float* as1   = (const float*)d_in[6];
    const float* ad1   = (const float*)d_in[7];
    const float* Wc2   = (const float*)d_in[8];
    const float* as2   = (const float*)d_in[9];
    const float* ad2   = (const float*)d_in[10];
    const float* Wn1   = (const float*)d_in[11];
    const float* Wn2   = (const float*)d_in[12];
    const float* Wout  = (const float*)d_in[13];
    float* out = (float*)d_out;

    // workspace layout (floats): total 17.28M floats = 69.12 MB
    float* A   = (float*)d_ws;        // 10.24M: hn [N,C,128]; later reused for conv outputs
    float* B   = A + 10240000;        // 5.12M : proj output h [N,C,64]
    float* es  = B + 5120000;         // 80k
    float* ed  = es + 80000;          // 80k
    unsigned* mm = (unsigned*)(ed + 80000);  // 80k
    float* den = (float*)(mm + 80000);       // 80k
    float* pex = den + 80000;                // 1.6M : per-edge logits -> exp
    float* C1  = A;                   // conv1 out [N,C,64] (hn region reuse)
    float* C2  = A + 5120000;         // conv2 out [N,C,64]

    dim3 blk(256);

    // LayerNorm
    ln_kernel<<<N_ATOMS * NCH / 4, blk, 0, stream>>>(x, gamma, beta, A);

    // ---- conv1 ----
    proj_kernel<128, false, true><<<N_ATOMS / 32, blk, 0, stream>>>(A, Wc1, as1, ad1, B, es, ed);
    fill_kernel<<<256, blk, 0, stream>>>(C1, N_ATOMS * 256, 0.f);
    fill_kernel<<<64, blk, 0, stream>>>((float*)mm, N_ATOMS * NCH, 0.f);  // enc(-inf)-ish floor
    fill_kernel<<<64, blk, 0, stream>>>(den, N_ATOMS * NCH, 0.f);
    edge_max_kernel<<<(N_EDGES + 255) / 256, blk, 0, stream>>>(ei, es, ed, mm, pex, N_EDGES);
    edge_sum_kernel<<<(N_EDGES + 255) / 256, blk, 0, stream>>>(ei, mm, pex, den, N_EDGES);
    edge_msg_kernel<<<N_EDGES, blk, 0, stream>>>(ei, pex, den, B, C1, N_EDGES);

    // ---- conv2 (silu fused on load) ----
    proj_kernel<64, true, true><<<N_ATOMS / 32, blk, 0, stream>>>(C1, Wc2, as2, ad2, B, es, ed);
    fill_kernel<<<256, blk, 0, stream>>>(C2, N_ATOMS * 256, 0.f);
    fill_kernel<<<64, blk, 0, stream>>>((float*)mm, N_ATOMS * NCH, 0.f);
    fill_kernel<<<64, blk, 0, stream>>>(den, N_ATOMS * NCH, 0.f);
    edge_max_kernel<<<(N_EDGES + 255) / 256, blk, 0, stream>>>(ei, es, ed, mm, pex, N_EDGES);
    edge_sum_kernel<<<(N_EDGES + 255) / 256, blk, 0, stream>>>(ei, mm, pex, den, N_EDGES);
    edge_msg_kernel<<<N_EDGES, blk, 0, stream>>>(ei, pex, den, B, C2, N_EDGES);

    // ---- MLP head + reductions (silu fused on load) ----
    fill_kernel<<<1, blk, 0, stream>>>(out, S_OUT, 0.f);
    mlp_kernel<<<(N_ATOMS + 255) / 256, blk, 0, stream>>>(C2, Wn1, Wn2, Wout, bat, out, N_ATOMS);
}

// Round 2
// 526.377 us; speedup vs baseline: 2.4197x; 2.4197x over previous
//
#include <hip/hip_runtime.h>
#include <hip/hip_bf16.h>

// Problem constants (match reference)
#define N_ATOMS 20000
#define N_EDGES 400000
#define NCH 4
#define F_IN 128
#define S_OUT 32

// ---------- helpers ----------
__device__ __forceinline__ float silu_f(float v) { return v / (1.f + __expf(-v)); }

// ---------- fill ----------
__global__ void fill_kernel(float* __restrict__ p, int n, float v) {
    int i = blockIdx.x * blockDim.x + threadIdx.x;
    int stride = gridDim.x * blockDim.x;
    for (; i < n; i += stride) p[i] = v;
}

// ---------- LayerNorm over last dim (128) ----------
__global__ __launch_bounds__(256) void ln_kernel(const float* __restrict__ x,
                                                 const float* __restrict__ gamma,
                                                 const float* __restrict__ beta,
                                                 float* __restrict__ out) {
    int row = blockIdx.x * 4 + (threadIdx.x >> 6);  // row in [0, N*C)
    int l = threadIdx.x & 63;
    const float* xr = x + (size_t)row * F_IN;
    float v0 = xr[l], v1 = xr[l + 64];
    float s = v0 + v1, sq = v0 * v0 + v1 * v1;
#pragma unroll
    for (int off = 32; off; off >>= 1) {
        s += __shfl_xor(s, off);
        sq += __shfl_xor(sq, off);
    }
    float mu = s * (1.f / 128.f);
    float var = sq * (1.f / 128.f) - mu * mu;
    float rs = rsqrtf(var + 1e-5f);
    float* orow = out + (size_t)row * F_IN;
    orow[l]      = (v0 - mu) * rs * gamma[l]      + beta[l];
    orow[l + 64] = (v1 - mu) * rs * gamma[l + 64] + beta[l + 64];
}

// ---------- per-channel projection: out[n,c,o]=sum_k in[n,c,k]W[c,k,o]; plus attn dots ----------
template <int FIN, bool SILU_IN, bool ATT>
__global__ __launch_bounds__(256) void proj_kernel(const float* __restrict__ in,
                                                   const float* __restrict__ W,
                                                   const float* __restrict__ a_src,
                                                   const float* __restrict__ a_dst,
                                                   float* __restrict__ out,
                                                   float* __restrict__ es,
                                                   float* __restrict__ ed) {
    __shared__ float Wl[FIN * 64];
    __shared__ float inl[32 * FIN];
    const int tid = threadIdx.x;
    const int n0 = blockIdx.x * 32;
    const int o = tid & 63;
    const int w = tid >> 6;

    for (int c = 0; c < NCH; ++c) {
        for (int i = tid; i < FIN * 64; i += 256) Wl[i] = W[c * FIN * 64 + i];
        for (int i = tid; i < 32 * FIN; i += 256) {
            int nl = i / FIN, k = i - nl * FIN;
            float v = in[(size_t)(n0 + nl) * (NCH * FIN) + c * FIN + k];
            if (SILU_IN) v = silu_f(v);
            inl[i] = v;
        }
        __syncthreads();

        float as = 0.f, ad = 0.f;
        if (ATT) { as = a_src[c * 64 + o]; ad = a_dst[c * 64 + o]; }

        float acc[8];
#pragma unroll
        for (int i = 0; i < 8; ++i) acc[i] = 0.f;
#pragma unroll 4
        for (int k = 0; k < FIN; ++k) {
            float wv = Wl[k * 64 + o];
#pragma unroll
            for (int i = 0; i < 8; ++i) acc[i] += inl[(w * 8 + i) * FIN + k] * wv;
        }
#pragma unroll
        for (int i = 0; i < 8; ++i) {
            int n = n0 + w * 8 + i;
            out[(size_t)n * 256 + c * 64 + o] = acc[i];
            if (ATT) {
                float vs = acc[i] * as, vd = acc[i] * ad;
#pragma unroll
                for (int off = 32; off; off >>= 1) {
                    vs += __shfl_xor(vs, off);
                    vd += __shfl_xor(vd, off);
                }
                if (o == 0) { es[n * NCH + c] = vs; ed[n * NCH + c] = vd; }
            }
        }
        __syncthreads();
    }
}

// ---------- CSR build: histogram -> scan -> scatter ----------
__global__ void hist_kernel(const int* __restrict__ ei, int* __restrict__ cnt, int E) {
    int e = blockIdx.x * 256 + threadIdx.x;
    if (e < E) atomicAdd(&cnt[ei[E + e]], 1);
}

// single-block exclusive scan over n counters -> rowp[0..n]
__global__ __launch_bounds__(256) void scan_kernel(const int* __restrict__ cnt,
                                                   int* __restrict__ rowp, int n) {
    __shared__ int buf[256];
    __shared__ int carry;
    if (threadIdx.x == 0) carry = 0;
    __syncthreads();
    for (int base = 0; base < n; base += 256) {
        int i = base + threadIdx.x;
        int v = (i < n) ? cnt[i] : 0;
        buf[threadIdx.x] = v;
        __syncthreads();
#pragma unroll
        for (int off = 1; off < 256; off <<= 1) {
            int t = (threadIdx.x >= off) ? buf[threadIdx.x - off] : 0;
            __syncthreads();
            buf[threadIdx.x] += t;
            __syncthreads();
        }
        int incl = buf[threadIdx.x];
        if (i < n) rowp[i] = carry + incl - v;
        __syncthreads();
        if (threadIdx.x == 255) carry += buf[255];
        __syncthreads();
    }
    if (threadIdx.x == 0) rowp[n] = carry;
}

__global__ void scatter_kernel(const int* __restrict__ ei, const int* __restrict__ rowp,
                               int* __restrict__ fill, int* __restrict__ csr_src, int E) {
    int e = blockIdx.x * 256 + threadIdx.x;
    if (e < E) {
        int d = ei[E + e];
        int pos = rowp[d] + atomicAdd(&fill[d], 1);
        csr_src[pos] = ei[e];
    }
}

// ---------- fused GAT aggregation (gather side): softmax + weighted sum ----------
// one block per dst node; 4 waves = 4 channels; 64 lanes dual-role (edges / features)
__global__ __launch_bounds__(256) void gat_gather_kernel(const int* __restrict__ rowp,
                                                         const int* __restrict__ csr_src,
                                                         const float* __restrict__ es,
                                                         const float* __restrict__ ed,
                                                         const float* __restrict__ h,
                                                         float* __restrict__ out) {
    int d = blockIdx.x;
    int c = threadIdx.x >> 6, o = threadIdx.x & 63;
    int r0 = rowp[d], r1 = rowp[d + 1];
    __shared__ int   ssrc[NCH][64];
    __shared__ float sex[NCH][64];
    float edc = ed[d * NCH + c];
    float m = -1e30f, den = 0.f, acc = 0.f;
    for (int base = r0; base < r1; base += 64) {
        int len = min(64, r1 - base);
        // phase A: lanes = edges
        float logit = -1e30f;
        int s = 0;
        if (o < len) {
            s = csr_src[base + o];
            float v = es[s * NCH + c] + edc;
            logit = v >= 0.f ? v : 0.2f * v;
        }
        float cm = logit;
#pragma unroll
        for (int off = 32; off; off >>= 1) cm = fmaxf(cm, __shfl_xor(cm, off));
        float nm = fmaxf(m, cm);
        float resc = __expf(m - nm);           // 0 on first chunk
        float ex = (o < len) ? __expf(logit - nm) : 0.f;
        float cs = ex;
#pragma unroll
        for (int off = 32; off; off >>= 1) cs += __shfl_xor(cs, off);
        den = den * resc + cs;
        acc *= resc;
        m = nm;
        ssrc[c][o] = s;
        sex[c][o] = ex;
        __syncthreads();
        // phase B: lanes = features
        for (int jj = 0; jj < len; ++jj) {
            int sj = ssrc[c][jj];
            acc += sex[c][jj] * h[(size_t)sj * 256 + c * 64 + o];
        }
        __syncthreads();
    }
    out[(size_t)d * 256 + c * 64 + o] = acc / (den + 1e-16f);
}

// ---------- MLP + channel-sum + structure segment-sum ----------
__global__ __launch_bounds__(256) void mlp_kernel(const float* __restrict__ in,
                                                  const float* __restrict__ W1,
                                                  const float* __restrict__ W2,
                                                  const float* __restrict__ W3,
                                                  const int* __restrict__ bat,
                                                  float* __restrict__ out, int N) {
    int n = blockIdx.x * 256 + threadIdx.x;
    bool act = n < N;
    int nn = act ? n : N - 1;
    float y = 0.f;
    for (int c = 0; c < NCH; ++c) {
        const float* ip = in + (size_t)nn * 256 + c * 64;
        const float* w1 = W1 + c * 4096;
        const float* w2 = W2 + c * 2048;
        const float* w3 = W3 + c * 32;
        float t1[64];
#pragma unroll
        for (int o = 0; o < 64; ++o) t1[o] = 0.f;
#pragma unroll
        for (int k = 0; k < 64; ++k) {
            float ak = silu_f(ip[k]);
#pragma unroll
            for (int o = 0; o < 64; ++o) t1[o] += ak * w1[k * 64 + o];
        }
        float t2[32];
#pragma unroll
        for (int o = 0; o < 32; ++o) t2[o] = 0.f;
#pragma unroll
        for (int k = 0; k < 64; ++k) {
            float tk = silu_f(t1[k]);
#pragma unroll
            for (int o = 0; o < 32; ++o) t2[o] += tk * w2[k * 32 + o];
        }
#pragma unroll
        for (int o = 0; o < 32; ++o) y += silu_f(t2[o]) * w3[o];
    }
    float contrib = act ? y * 0.025f : 0.f;  // /sqrt(4)/20
    int b = bat[nn];
    int b0 = __shfl(b, 0);
    bool uni = __all(b == b0);
    if (uni) {
        float t = contrib;
#pragma unroll
        for (int off = 32; off; off >>= 1) t += __shfl_xor(t, off);
        if ((threadIdx.x & 63) == 0) atomicAdd(out + b0, t);
    } else {
        if (act) atomicAdd(out + b, contrib);
    }
}

extern "C" void kernel_launch(void* const* d_in, const int* in_sizes, int n_in,
                              void* d_out, int out_size, void* d_ws, size_t ws_size,
                              hipStream_t stream) {
    const float* x     = (const float*)d_in[0];
    const int*   ei    = (const int*)d_in[1];
    const int*   bat   = (const int*)d_in[2];
    const float* gamma = (const float*)d_in[3];
    const float* beta  = (const float*)d_in[4];
    const float* Wc1   = (const float*)d_in[5];
    const float* as1   = (const float*)d_in[6];
    const float* ad1   = (const float*)d_in[7];
    const float* Wc2   = (const float*)d_in[8];
    const float* as2   = (const float*)d_in[9];
    const float* ad2   = (const float*)d_in[10];
    const float* Wn1   = (const float*)d_in[11];
    const float* Wn2   = (const float*)d_in[12];
    const float* Wout  = (const float*)d_in[13];
    float* out = (float*)d_out;

    // workspace layout (floats)
    float* A    = (float*)d_ws;            // 10.24M: LN out [N,C,128]; reused for conv outs
    float* B    = A + 10240000;            // 5.12M : proj output h [N,C,64]
    float* es   = B + 5120000;             // 80k
    float* ed   = es + 80000;              // 80k
    int* rowp   = (int*)(ed + 80000);      // 20001
    int* cnt    = rowp + 20004;            // 20000
    int* fillc  = cnt + 20000;             // 20000
    int* csr    = fillc + 20000;           // 400000
    float* C1   = A;                       // conv1 out [N,C,64]
    float* C2   = A + 5120000;             // conv2 out [N,C,64]

    dim3 blk(256);

    // ---- CSR build (graph is shared by both convs) ----
    fill_kernel<<<40, blk, 0, stream>>>((float*)cnt, 20000, 0.f);
    fill_kernel<<<40, blk, 0, stream>>>((float*)fillc, 20000, 0.f);
    hist_kernel<<<(N_EDGES + 255) / 256, blk, 0, stream>>>(ei, cnt, N_EDGES);
    scan_kernel<<<1, blk, 0, stream>>>(cnt, rowp, N_ATOMS);
    scatter_kernel<<<(N_EDGES + 255) / 256, blk, 0, stream>>>(ei, rowp, fillc, csr, N_EDGES);

    // ---- LayerNorm ----
    ln_kernel<<<N_ATOMS * NCH / 4, blk, 0, stream>>>(x, gamma, beta, A);

    // ---- conv1 ----
    proj_kernel<128, false, true><<<N_ATOMS / 32, blk, 0, stream>>>(A, Wc1, as1, ad1, B, es, ed);
    gat_gather_kernel<<<N_ATOMS, blk, 0, stream>>>(rowp, csr, es, ed, B, C1);

    // ---- conv2 (silu fused on load) ----
    proj_kernel<64, true, true><<<N_ATOMS / 32, blk, 0, stream>>>(C1, Wc2, as2, ad2, B, es, ed);
    gat_gather_kernel<<<N_ATOMS, blk, 0, stream>>>(rowp, csr, es, ed, B, C2);

    // ---- MLP head + reductions (silu fused on load) ----
    fill_kernel<<<1, blk, 0, stream>>>(out, S_OUT, 0.f);
    mlp_kernel<<<(N_ATOMS + 255) / 256, blk, 0, stream>>>(C2, Wn1, Wn2, Wout, bat, out, N_ATOMS);
}

// Round 3
// 434.799 us; speedup vs baseline: 2.9293x; 1.2106x over previous
//
#include <hip/hip_runtime.h>
#include <hip/hip_bf16.h>

// Problem constants (match reference)
#define N_ATOMS 20000
#define N_EDGES 400000
#define NCH 4
#define F_IN 128
#define S_OUT 32

// ---------- helpers ----------
__device__ __forceinline__ float silu_f(float v) { return v / (1.f + __expf(-v)); }

// ---------- fill ----------
__global__ void fill_kernel(float* __restrict__ p, int n, float v) {
    int i = blockIdx.x * blockDim.x + threadIdx.x;
    int stride = gridDim.x * blockDim.x;
    for (; i < n; i += stride) p[i] = v;
}

// ---------- LayerNorm over last dim (128) ----------
__global__ __launch_bounds__(256) void ln_kernel(const float* __restrict__ x,
                                                 const float* __restrict__ gamma,
                                                 const float* __restrict__ beta,
                                                 float* __restrict__ out) {
    int row = blockIdx.x * 4 + (threadIdx.x >> 6);  // row in [0, N*C)
    int l = threadIdx.x & 63;
    const float* xr = x + (size_t)row * F_IN;
    float v0 = xr[l], v1 = xr[l + 64];
    float s = v0 + v1, sq = v0 * v0 + v1 * v1;
#pragma unroll
    for (int off = 32; off; off >>= 1) {
        s += __shfl_xor(s, off);
        sq += __shfl_xor(sq, off);
    }
    float mu = s * (1.f / 128.f);
    float var = sq * (1.f / 128.f) - mu * mu;
    float rs = rsqrtf(var + 1e-5f);
    float* orow = out + (size_t)row * F_IN;
    orow[l]      = (v0 - mu) * rs * gamma[l]      + beta[l];
    orow[l + 64] = (v1 - mu) * rs * gamma[l + 64] + beta[l + 64];
}

// ---------- per-channel projection: out[n,c,o]=sum_k in[n,c,k]W[c,k,o]; plus attn dots ----------
template <int FIN, bool SILU_IN, bool ATT>
__global__ __launch_bounds__(256) void proj_kernel(const float* __restrict__ in,
                                                   const float* __restrict__ W,
                                                   const float* __restrict__ a_src,
                                                   const float* __restrict__ a_dst,
                                                   float* __restrict__ out,
                                                   float* __restrict__ es,
                                                   float* __restrict__ ed) {
    __shared__ float Wl[FIN * 64];
    __shared__ float inl[32 * FIN];
    const int tid = threadIdx.x;
    const int n0 = blockIdx.x * 32;
    const int o = tid & 63;
    const int w = tid >> 6;

    for (int c = 0; c < NCH; ++c) {
        for (int i = tid; i < FIN * 64; i += 256) Wl[i] = W[c * FIN * 64 + i];
        for (int i = tid; i < 32 * FIN; i += 256) {
            int nl = i / FIN, k = i - nl * FIN;
            float v = in[(size_t)(n0 + nl) * (NCH * FIN) + c * FIN + k];
            if (SILU_IN) v = silu_f(v);
            inl[i] = v;
        }
        __syncthreads();

        float as = 0.f, ad = 0.f;
        if (ATT) { as = a_src[c * 64 + o]; ad = a_dst[c * 64 + o]; }

        float acc[8];
#pragma unroll
        for (int i = 0; i < 8; ++i) acc[i] = 0.f;
#pragma unroll 4
        for (int k = 0; k < FIN; ++k) {
            float wv = Wl[k * 64 + o];
#pragma unroll
            for (int i = 0; i < 8; ++i) acc[i] += inl[(w * 8 + i) * FIN + k] * wv;
        }
#pragma unroll
        for (int i = 0; i < 8; ++i) {
            int n = n0 + w * 8 + i;
            out[(size_t)n * 256 + c * 64 + o] = acc[i];
            if (ATT) {
                float vs = acc[i] * as, vd = acc[i] * ad;
#pragma unroll
                for (int off = 32; off; off >>= 1) {
                    vs += __shfl_xor(vs, off);
                    vd += __shfl_xor(vd, off);
                }
                if (o == 0) { es[n * NCH + c] = vs; ed[n * NCH + c] = vd; }
            }
        }
        __syncthreads();
    }
}

// ---------- CSR build: histogram -> scan -> scatter ----------
__global__ void hist_kernel(const int* __restrict__ ei, int* __restrict__ cnt, int E) {
    int e = blockIdx.x * 256 + threadIdx.x;
    if (e < E) atomicAdd(&cnt[ei[E + e]], 1);
}

// single-block exclusive scan over n counters -> rowp[0..n]
__global__ __launch_bounds__(256) void scan_kernel(const int* __restrict__ cnt,
                                                   int* __restrict__ rowp, int n) {
    __shared__ int buf[256];
    __shared__ int carry;
    if (threadIdx.x == 0) carry = 0;
    __syncthreads();
    for (int base = 0; base < n; base += 256) {
        int i = base + threadIdx.x;
        int v = (i < n) ? cnt[i] : 0;
        buf[threadIdx.x] = v;
        __syncthreads();
#pragma unroll
        for (int off = 1; off < 256; off <<= 1) {
            int t = (threadIdx.x >= off) ? buf[threadIdx.x - off] : 0;
            __syncthreads();
            buf[threadIdx.x] += t;
            __syncthreads();
        }
        int incl = buf[threadIdx.x];
        if (i < n) rowp[i] = carry + incl - v;
        __syncthreads();
        if (threadIdx.x == 255) carry += buf[255];
        __syncthreads();
    }
    if (threadIdx.x == 0) rowp[n] = carry;
}

__global__ void scatter_kernel(const int* __restrict__ ei, const int* __restrict__ rowp,
                               int* __restrict__ fill, int* __restrict__ csr_src, int E) {
    int e = blockIdx.x * 256 + threadIdx.x;
    if (e < E) {
        int d = ei[E + e];
        int pos = rowp[d] + atomicAdd(&fill[d], 1);
        csr_src[pos] = ei[e];
    }
}

// ---------- fused GAT aggregation (gather side): softmax + weighted sum ----------
// one block per dst node; 4 waves = 4 channels; 64 lanes dual-role (edges / features)
__global__ __launch_bounds__(256) void gat_gather_kernel(const int* __restrict__ rowp,
                                                         const int* __restrict__ csr_src,
                                                         const float* __restrict__ es,
                                                         const float* __restrict__ ed,
                                                         const float* __restrict__ h,
                                                         float* __restrict__ out) {
    int d = blockIdx.x;
    int c = threadIdx.x >> 6, o = threadIdx.x & 63;
    int r0 = rowp[d], r1 = rowp[d + 1];
    __shared__ int   ssrc[NCH][64];
    __shared__ float sex[NCH][64];
    float edc = ed[d * NCH + c];
    float m = -1e30f, den = 0.f, acc = 0.f;
    for (int base = r0; base < r1; base += 64) {
        int len = min(64, r1 - base);
        // phase A: lanes = edges
        float logit = -1e30f;
        int s = 0;
        if (o < len) {
            s = csr_src[base + o];
            float v = es[s * NCH + c] + edc;
            logit = v >= 0.f ? v : 0.2f * v;
        }
        float cm = logit;
#pragma unroll
        for (int off = 32; off; off >>= 1) cm = fmaxf(cm, __shfl_xor(cm, off));
        float nm = fmaxf(m, cm);
        float resc = __expf(m - nm);           // 0 on first chunk
        float ex = (o < len) ? __expf(logit - nm) : 0.f;
        float cs = ex;
#pragma unroll
        for (int off = 32; off; off >>= 1) cs += __shfl_xor(cs, off);
        den = den * resc + cs;
        acc *= resc;
        m = nm;
        ssrc[c][o] = s;
        sex[c][o] = ex;
        __syncthreads();
        // phase B: lanes = features
        for (int jj = 0; jj < len; ++jj) {
            int sj = ssrc[c][jj];
            acc += sex[c][jj] * h[(size_t)sj * 256 + c * 64 + o];
        }
        __syncthreads();
    }
    out[(size_t)d * 256 + c * 64 + o] = acc / (den + 1e-16f);
}

// ---------- MLP + channel-sum + structure segment-sum ----------
// one block per 32 nodes; weights staged in LDS; no per-thread arrays (no scratch)
__global__ __launch_bounds__(256) void mlp_kernel(const float* __restrict__ in,
                                                  const float* __restrict__ W1,
                                                  const float* __restrict__ W2,
                                                  const float* __restrict__ W3,
                                                  const int* __restrict__ bat,
                                                  float* __restrict__ out, int N) {
    __shared__ float W1l[64 * 64];
    __shared__ float W2l[64 * 32];
    __shared__ float w3l[32];
    __shared__ float inl[32 * 64];
    __shared__ float t1l[32 * 64];
    __shared__ float ynode[32];
    const int tid = threadIdx.x;
    const int n0 = blockIdx.x * 32;
    const int o = tid & 63;
    const int w = tid >> 6;

    if (tid < 32) ynode[tid] = 0.f;

    for (int c = 0; c < NCH; ++c) {
        for (int i = tid; i < 4096; i += 256) W1l[i] = W1[c * 4096 + i];
        for (int i = tid; i < 2048; i += 256) W2l[i] = W2[c * 2048 + i];
        if (tid < 32) w3l[tid] = W3[c * 32 + tid];
        for (int i = tid; i < 2048; i += 256) {
            int nl = i >> 6, k = i & 63;
            inl[i] = silu_f(in[(size_t)(n0 + nl) * 256 + c * 64 + k]);
        }
        __syncthreads();

        // layer 1: each wave does 8 nodes, lane = output feature
        float acc[8];
#pragma unroll
        for (int i = 0; i < 8; ++i) acc[i] = 0.f;
#pragma unroll 4
        for (int k = 0; k < 64; ++k) {
            float wv = W1l[k * 64 + o];
#pragma unroll
            for (int i = 0; i < 8; ++i) acc[i] += inl[(w * 8 + i) * 64 + k] * wv;
        }
#pragma unroll
        for (int i = 0; i < 8; ++i) t1l[(w * 8 + i) * 64 + o] = silu_f(acc[i]);
        __syncthreads();

        // layers 2+3: half-wave per node (h = lane>>5 selects node, o2 = lane&31 = output)
        int h = o >> 5, o2 = o & 31;
#pragma unroll
        for (int it = 0; it < 4; ++it) {
            int nl = w * 8 + it * 2 + h;
            float a2 = 0.f;
#pragma unroll 8
            for (int k = 0; k < 64; ++k) a2 += t1l[nl * 64 + k] * W2l[k * 32 + o2];
            float t = silu_f(a2) * w3l[o2];
#pragma unroll
            for (int off = 16; off; off >>= 1) t += __shfl_xor(t, off);
            if (o2 == 0) ynode[nl] += t;  // each (wave, it, h) owns distinct nl
        }
        __syncthreads();
    }

    // energies: batch-uniform fast path (batch_ids sorted); grid is exactly N/32
    if (tid < 64) {
        int l = tid & 63;
        int n = n0 + (l & 31);
        float val = (l < 32) ? ynode[l] * 0.025f : 0.f;  // /sqrt(4)/20
        int b = bat[n];
        int b0 = __shfl(b, 0);
        if (__all(b == b0)) {
            float t = val;
#pragma unroll
            for (int off = 32; off; off >>= 1) t += __shfl_xor(t, off);
            if (l == 0) atomicAdd(out + b0, t);
        } else if (l < 32) {
            atomicAdd(out + b, val);
        }
    }
}

extern "C" void kernel_launch(void* const* d_in, const int* in_sizes, int n_in,
                              void* d_out, int out_size, void* d_ws, size_t ws_size,
                              hipStream_t stream) {
    const float* x     = (const float*)d_in[0];
    const int*   ei    = (const int*)d_in[1];
    const int*   bat   = (const int*)d_in[2];
    const float* gamma = (const float*)d_in[3];
    const float* beta  = (const float*)d_in[4];
    const float* Wc1   = (const float*)d_in[5];
    const float* as1   = (const float*)d_in[6];
    const float* ad1   = (const float*)d_in[7];
    const float* Wc2   = (const float*)d_in[8];
    const float* as2   = (const float*)d_in[9];
    const float* ad2   = (const float*)d_in[10];
    const float* Wn1   = (const float*)d_in[11];
    const float* Wn2   = (const float*)d_in[12];
    const float* Wout  = (const float*)d_in[13];
    float* out = (float*)d_out;

    // workspace layout (floats)
    float* A    = (float*)d_ws;            // 10.24M: LN out [N,C,128]; reused for conv outs
    float* B    = A + 10240000;            // 5.12M : proj output h [N,C,64]
    float* es   = B + 5120000;             // 80k
    float* ed   = es + 80000;              // 80k
    int* rowp   = (int*)(ed + 80000);      // 20001
    int* cnt    = rowp + 20004;            // 20000
    int* fillc  = cnt + 20000;             // 20000
    int* csr    = fillc + 20000;           // 400000
    float* C1   = A;                       // conv1 out [N,C,64]
    float* C2   = A + 5120000;             // conv2 out [N,C,64]

    dim3 blk(256);

    // ---- CSR build (graph is shared by both convs) ----
    fill_kernel<<<40, blk, 0, stream>>>((float*)cnt, 20000, 0.f);
    fill_kernel<<<40, blk, 0, stream>>>((float*)fillc, 20000, 0.f);
    hist_kernel<<<(N_EDGES + 255) / 256, blk, 0, stream>>>(ei, cnt, N_EDGES);
    scan_kernel<<<1, blk, 0, stream>>>(cnt, rowp, N_ATOMS);
    scatter_kernel<<<(N_EDGES + 255) / 256, blk, 0, stream>>>(ei, rowp, fillc, csr, N_EDGES);

    // ---- LayerNorm ----
    ln_kernel<<<N_ATOMS * NCH / 4, blk, 0, stream>>>(x, gamma, beta, A);

    // ---- conv1 ----
    proj_kernel<128, false, true><<<N_ATOMS / 32, blk, 0, stream>>>(A, Wc1, as1, ad1, B, es, ed);
    gat_gather_kernel<<<N_ATOMS, blk, 0, stream>>>(rowp, csr, es, ed, B, C1);

    // ---- conv2 (silu fused on load) ----
    proj_kernel<64, true, true><<<N_ATOMS / 32, blk, 0, stream>>>(C1, Wc2, as2, ad2, B, es, ed);
    gat_gather_kernel<<<N_ATOMS, blk, 0, stream>>>(rowp, csr, es, ed, B, C2);

    // ---- MLP head + reductions (silu fused on load) ----
    fill_kernel<<<1, blk, 0, stream>>>(out, S_OUT, 0.f);
    mlp_kernel<<<N_ATOMS / 32, blk, 0, stream>>>(C2, Wn1, Wn2, Wout, bat, out, N_ATOMS);
}

// Round 4
// 352.523 us; speedup vs baseline: 3.6130x; 1.2334x over previous
//
#include <hip/hip_runtime.h>
#include <hip/hip_bf16.h>

// Problem constants (match reference)
#define N_ATOMS 20000
#define N_EDGES 400000
#define NCH 4
#define F_IN 128
#define S_OUT 32

// ---------- helpers ----------
__device__ __forceinline__ float silu_f(float v) { return v / (1.f + __expf(-v)); }

__device__ __forceinline__ int wave_iscan(int v, int l) {
#pragma unroll
    for (int off = 1; off < 64; off <<= 1) {
        int t = __shfl_up(v, off);
        if (l >= off) v += t;
    }
    return v;
}

// ---------- fill ----------
__global__ void fill_kernel(float* __restrict__ p, int n, float v) {
    int i = blockIdx.x * blockDim.x + threadIdx.x;
    int stride = gridDim.x * blockDim.x;
    for (; i < n; i += stride) p[i] = v;
}

// ---------- LayerNorm over last dim (128) ----------
__global__ __launch_bounds__(256) void ln_kernel(const float* __restrict__ x,
                                                 const float* __restrict__ gamma,
                                                 const float* __restrict__ beta,
                                                 float* __restrict__ out) {
    int row = blockIdx.x * 4 + (threadIdx.x >> 6);  // row in [0, N*C)
    int l = threadIdx.x & 63;
    const float* xr = x + (size_t)row * F_IN;
    float v0 = xr[l], v1 = xr[l + 64];
    float s = v0 + v1, sq = v0 * v0 + v1 * v1;
#pragma unroll
    for (int off = 32; off; off >>= 1) {
        s += __shfl_xor(s, off);
        sq += __shfl_xor(sq, off);
    }
    float mu = s * (1.f / 128.f);
    float var = sq * (1.f / 128.f) - mu * mu;
    float rs = rsqrtf(var + 1e-5f);
    float* orow = out + (size_t)row * F_IN;
    orow[l]      = (v0 - mu) * rs * gamma[l]      + beta[l];
    orow[l + 64] = (v1 - mu) * rs * gamma[l + 64] + beta[l + 64];
}

// ---------- per-channel projection: out[n,c,o]=sum_k in[n,c,k]W[c,k,o]; plus attn dots ----------
template <int FIN, bool SILU_IN, bool ATT>
__global__ __launch_bounds__(256) void proj_kernel(const float* __restrict__ in,
                                                   const float* __restrict__ W,
                                                   const float* __restrict__ a_src,
                                                   const float* __restrict__ a_dst,
                                                   float* __restrict__ out,
                                                   float* __restrict__ es,
                                                   float* __restrict__ ed) {
    __shared__ float Wl[FIN * 64];
    __shared__ float inl[32 * FIN];
    const int tid = threadIdx.x;
    const int n0 = blockIdx.x * 32;
    const int o = tid & 63;
    const int w = tid >> 6;

    for (int c = 0; c < NCH; ++c) {
        for (int i = tid; i < FIN * 64; i += 256) Wl[i] = W[c * FIN * 64 + i];
        for (int i = tid; i < 32 * FIN; i += 256) {
            int nl = i / FIN, k = i - nl * FIN;
            float v = in[(size_t)(n0 + nl) * (NCH * FIN) + c * FIN + k];
            if (SILU_IN) v = silu_f(v);
            inl[i] = v;
        }
        __syncthreads();

        float as = 0.f, ad = 0.f;
        if (ATT) { as = a_src[c * 64 + o]; ad = a_dst[c * 64 + o]; }

        float acc[8];
#pragma unroll
        for (int i = 0; i < 8; ++i) acc[i] = 0.f;
#pragma unroll 4
        for (int k = 0; k < FIN; ++k) {
            float wv = Wl[k * 64 + o];
#pragma unroll
            for (int i = 0; i < 8; ++i) acc[i] += inl[(w * 8 + i) * FIN + k] * wv;
        }
#pragma unroll
        for (int i = 0; i < 8; ++i) {
            int n = n0 + w * 8 + i;
            out[(size_t)n * 256 + c * 64 + o] = acc[i];
            if (ATT) {
                float vs = acc[i] * as, vd = acc[i] * ad;
#pragma unroll
                for (int off = 32; off; off >>= 1) {
                    vs += __shfl_xor(vs, off);
                    vd += __shfl_xor(vd, off);
                }
                if (o == 0) { es[n * NCH + c] = vs; ed[n * NCH + c] = vd; }
            }
        }
        __syncthreads();
    }
}

// ---------- CSR build: histogram -> hierarchical scan -> scatter ----------
__global__ void hist_kernel(const int* __restrict__ ei, int* __restrict__ cnt, int E) {
    int e = blockIdx.x * 256 + threadIdx.x;
    if (e < E) atomicAdd(&cnt[ei[E + e]], 1);
}

__global__ __launch_bounds__(256) void scan_l1_kernel(const int* __restrict__ cnt,
                                                      int* __restrict__ rowp,
                                                      int* __restrict__ bsum, int n) {
    int i = blockIdx.x * 256 + threadIdx.x;
    int l = threadIdx.x & 63, w = threadIdx.x >> 6;
    int v = (i < n) ? cnt[i] : 0;
    int incl = wave_iscan(v, l);
    __shared__ int wsum[4];
    if (l == 63) wsum[w] = incl;
    __syncthreads();
    int add = 0;
#pragma unroll
    for (int j = 0; j < 4; ++j) add += (j < w) ? wsum[j] : 0;
    if (i < n) rowp[i] = add + incl - v;
    if (threadIdx.x == 255) bsum[blockIdx.x] = add + incl;
}

__global__ __launch_bounds__(256) void scan_l2_kernel(const int* __restrict__ bsum,
                                                      int* __restrict__ boff,
                                                      int* __restrict__ rowp_n, int nb) {
    int i = threadIdx.x;
    int l = i & 63, w = i >> 6;
    int v = (i < nb) ? bsum[i] : 0;
    int incl = wave_iscan(v, l);
    __shared__ int wsum[4];
    if (l == 63) wsum[w] = incl;
    __syncthreads();
    int add = 0;
#pragma unroll
    for (int j = 0; j < 4; ++j) add += (j < w) ? wsum[j] : 0;
    if (i < nb) boff[i] = add + incl - v;
    if (i == nb - 1) *rowp_n = add + incl;
}

__global__ __launch_bounds__(256) void scan_l3_kernel(int* __restrict__ rowp,
                                                      const int* __restrict__ boff, int n) {
    int i = blockIdx.x * 256 + threadIdx.x;
    if (i < n) rowp[i] += boff[blockIdx.x];
}

__global__ void scatter_kernel(const int* __restrict__ ei, const int* __restrict__ rowp,
                               int* __restrict__ fill, int* __restrict__ csr_src, int E) {
    int e = blockIdx.x * 256 + threadIdx.x;
    if (e < E) {
        int d = ei[E + e];
        int pos = rowp[d] + atomicAdd(&fill[d], 1);
        csr_src[pos] = ei[e];
    }
}

// ---------- fused GAT aggregation (gather side): softmax + weighted sum ----------
// one block per dst node; 4 waves = 4 channels; 64 lanes dual-role (edges / features)
__global__ __launch_bounds__(256) void gat_gather_kernel(const int* __restrict__ rowp,
                                                         const int* __restrict__ csr_src,
                                                         const float* __restrict__ es,
                                                         const float* __restrict__ ed,
                                                         const float* __restrict__ h,
                                                         float* __restrict__ out) {
    int d = blockIdx.x;
    int c = threadIdx.x >> 6, o = threadIdx.x & 63;
    int r0 = rowp[d], r1 = rowp[d + 1];
    __shared__ int   ssrc[NCH][64];
    __shared__ float sex[NCH][64];
    float edc = ed[d * NCH + c];
    float m = -1e30f, den = 0.f, acc = 0.f;
    for (int base = r0; base < r1; base += 64) {
        int len = min(64, r1 - base);
        // phase A: lanes = edges
        float logit = -1e30f;
        int s = 0;
        if (o < len) {
            s = csr_src[base + o];
            float v = es[s * NCH + c] + edc;
            logit = v >= 0.f ? v : 0.2f * v;
        }
        float cm = logit;
#pragma unroll
        for (int off = 32; off; off >>= 1) cm = fmaxf(cm, __shfl_xor(cm, off));
        float nm = fmaxf(m, cm);
        float resc = __expf(m - nm);           // 0 on first chunk
        float ex = (o < len) ? __expf(logit - nm) : 0.f;
        float cs = ex;
#pragma unroll
        for (int off = 32; off; off >>= 1) cs += __shfl_xor(cs, off);
        den = den * resc + cs;
        acc *= resc;
        m = nm;
        ssrc[c][o] = s;
        sex[c][o] = ex;
        __syncthreads();
        // phase B: lanes = features
        for (int jj = 0; jj < len; ++jj) {
            int sj = ssrc[c][jj];
            acc += sex[c][jj] * h[(size_t)sj * 256 + c * 64 + o];
        }
        __syncthreads();
    }
    out[(size_t)d * 256 + c * 64 + o] = acc / (den + 1e-16f);
}

// ---------- MLP + channel-sum + structure segment-sum ----------
// one block per 32 nodes; weights staged in LDS; no per-thread arrays (no scratch)
__global__ __launch_bounds__(256) void mlp_kernel(const float* __restrict__ in,
                                                  const float* __restrict__ W1,
                                                  const float* __restrict__ W2,
                                                  const float* __restrict__ W3,
                                                  const int* __restrict__ bat,
                                                  float* __restrict__ out, int N) {
    __shared__ float W1l[64 * 64];
    __shared__ float W2l[64 * 32];
    __shared__ float w3l[32];
    __shared__ float inl[32 * 64];
    __shared__ float t1l[32 * 64];
    __shared__ float ynode[32];
    const int tid = threadIdx.x;
    const int n0 = blockIdx.x * 32;
    const int o = tid & 63;
    const int w = tid >> 6;

    if (tid < 32) ynode[tid] = 0.f;

    for (int c = 0; c < NCH; ++c) {
        for (int i = tid; i < 4096; i += 256) W1l[i] = W1[c * 4096 + i];
        for (int i = tid; i < 2048; i += 256) W2l[i] = W2[c * 2048 + i];
        if (tid < 32) w3l[tid] = W3[c * 32 + tid];
        for (int i = tid; i < 2048; i += 256) {
            int nl = i >> 6, k = i & 63;
            inl[i] = silu_f(in[(size_t)(n0 + nl) * 256 + c * 64 + k]);
        }
        __syncthreads();

        // layer 1: each wave does 8 nodes, lane = output feature
        float acc[8];
#pragma unroll
        for (int i = 0; i < 8; ++i) acc[i] = 0.f;
#pragma unroll 4
        for (int k = 0; k < 64; ++k) {
            float wv = W1l[k * 64 + o];
#pragma unroll
            for (int i = 0; i < 8; ++i) acc[i] += inl[(w * 8 + i) * 64 + k] * wv;
        }
#pragma unroll
        for (int i = 0; i < 8; ++i) t1l[(w * 8 + i) * 64 + o] = silu_f(acc[i]);
        __syncthreads();

        // layers 2+3: half-wave per node (h = lane>>5 selects node, o2 = lane&31 = output)
        int h = o >> 5, o2 = o & 31;
#pragma unroll
        for (int it = 0; it < 4; ++it) {
            int nl = w * 8 + it * 2 + h;
            float a2 = 0.f;
#pragma unroll 8
            for (int k = 0; k < 64; ++k) a2 += t1l[nl * 64 + k] * W2l[k * 32 + o2];
            float t = silu_f(a2) * w3l[o2];
#pragma unroll
            for (int off = 16; off; off >>= 1) t += __shfl_xor(t, off);
            if (o2 == 0) ynode[nl] += t;  // each (wave, it, h) owns distinct nl
        }
        __syncthreads();
    }

    // energies: batch-uniform fast path (batch_ids sorted); grid is exactly N/32
    if (tid < 64) {
        int l = tid & 63;
        int n = n0 + (l & 31);
        float val = (l < 32) ? ynode[l] * 0.025f : 0.f;  // /sqrt(4)/20
        int b = bat[n];
        int b0 = __shfl(b, 0);
        if (__all(b == b0)) {
            float t = val;
#pragma unroll
            for (int off = 32; off; off >>= 1) t += __shfl_xor(t, off);
            if (l == 0) atomicAdd(out + b0, t);
        } else if (l < 32) {
            atomicAdd(out + b, val);
        }
    }
}

extern "C" void kernel_launch(void* const* d_in, const int* in_sizes, int n_in,
                              void* d_out, int out_size, void* d_ws, size_t ws_size,
                              hipStream_t stream) {
    const float* x     = (const float*)d_in[0];
    const int*   ei    = (const int*)d_in[1];
    const int*   bat   = (const int*)d_in[2];
    const float* gamma = (const float*)d_in[3];
    const float* beta  = (const float*)d_in[4];
    const float* Wc1   = (const float*)d_in[5];
    const float* as1   = (const float*)d_in[6];
    const float* ad1   = (const float*)d_in[7];
    const float* Wc2   = (const float*)d_in[8];
    const float* as2   = (const float*)d_in[9];
    const float* ad2   = (const float*)d_in[10];
    const float* Wn1   = (const float*)d_in[11];
    const float* Wn2   = (const float*)d_in[12];
    const float* Wout  = (const float*)d_in[13];
    float* out = (float*)d_out;

    // workspace layout (floats)
    float* A    = (float*)d_ws;            // 10.24M: LN out [N,C,128]; reused for conv outs
    float* B    = A + 10240000;            // 5.12M : proj output h [N,C,64]
    float* es   = B + 5120000;             // 80k
    float* ed   = es + 80000;              // 80k
    int* rowp   = (int*)(ed + 80000);      // 20001 (pad 20004)
    int* cnt    = rowp + 20004;            // 20000
    int* fillc  = cnt + 20000;             // 20000
    int* csr    = fillc + 20000;           // 400000
    int* bsum   = csr + 400000;            // 128
    int* boff   = bsum + 128;              // 128
    float* C1   = A;                       // conv1 out [N,C,64]
    float* C2   = A + 5120000;             // conv2 out [N,C,64]

    dim3 blk(256);
    const int NB = (N_ATOMS + 255) / 256;  // 79

    // ---- CSR build (graph is shared by both convs) ----
    fill_kernel<<<80, blk, 0, stream>>>((float*)cnt, 40000, 0.f);  // cnt + fillc (adjacent)
    hist_kernel<<<(N_EDGES + 255) / 256, blk, 0, stream>>>(ei, cnt, N_EDGES);
    scan_l1_kernel<<<NB, blk, 0, stream>>>(cnt, rowp, bsum, N_ATOMS);
    scan_l2_kernel<<<1, blk, 0, stream>>>(bsum, boff, rowp + N_ATOMS, NB);
    scan_l3_kernel<<<NB, blk, 0, stream>>>(rowp, boff, N_ATOMS);
    scatter_kernel<<<(N_EDGES + 255) / 256, blk, 0, stream>>>(ei, rowp, fillc, csr, N_EDGES);

    // ---- LayerNorm ----
    ln_kernel<<<N_ATOMS * NCH / 4, blk, 0, stream>>>(x, gamma, beta, A);

    // ---- conv1 ----
    proj_kernel<128, false, true><<<N_ATOMS / 32, blk, 0, stream>>>(A, Wc1, as1, ad1, B, es, ed);
    gat_gather_kernel<<<N_ATOMS, blk, 0, stream>>>(rowp, csr, es, ed, B, C1);

    // ---- conv2 (silu fused on load) ----
    proj_kernel<64, true, true><<<N_ATOMS / 32, blk, 0, stream>>>(C1, Wc2, as2, ad2, B, es, ed);
    gat_gather_kernel<<<N_ATOMS, blk, 0, stream>>>(rowp, csr, es, ed, B, C2);

    // ---- MLP head + reductions (silu fused on load) ----
    fill_kernel<<<1, blk, 0, stream>>>(out, S_OUT, 0.f);
    mlp_kernel<<<N_ATOMS / 32, blk, 0, stream>>>(C2, Wn1, Wn2, Wout, bat, out, N_ATOMS);
}